// Round 9
// baseline (376.467 us; speedup 1.0000x reference)
//
#include <hip/hip_runtime.h>

typedef unsigned short ushort_t;
typedef short v8s __attribute__((ext_vector_type(8)));   // 8 bf16 (4 VGPRs)
typedef float v4f __attribute__((ext_vector_type(4)));   // MFMA acc

#define BATCH    65536
#define UNITS    256
#define GT_STRIDE 264        // shorts per LDS row (528 B)

__device__ __forceinline__ float b2f(ushort_t u) {
    union { unsigned int i; float f; } v; v.i = ((unsigned int)u) << 16; return v.f;
}
__device__ __forceinline__ ushort_t f2b(float f) {
    union { float f; unsigned int i; } v; v.f = f;
    unsigned int r = (v.i + 0x7fffu + ((v.i >> 16) & 1u)) >> 16;   // RNE
    return (ushort_t)r;
}

// ---- weight pre-pack: fp32 W[512][256] -> bf16 MFMA-fragment order ---------
// B frag for (kchunk s = k>>5, tile t = n>>4): lane l = q*16+n16 holds
// B[k = s*32+q*8+j][n = t*16+n16], j=0..7.  Layout [s][t][l][8] -> a wave's
// B load is base + l*16B: perfectly coalesced 1KB, sequential lines.
__global__ void pack_w(const float* __restrict__ w_in,
                       const float* __restrict__ w_rec,
                       ushort_t* __restrict__ Wp) {
    int gid = blockIdx.x * 256 + threadIdx.x;      // 0..131071
    int k = gid >> 8, n = gid & 255;
    float v = (k < 256) ? w_in[k * 256 + n] : w_rec[(k - 256) * 256 + n];
    int s = k >> 5, t = n >> 4;
    int lane = ((k >> 3) & 3) * 16 + (n & 15);
    Wp[(size_t)(((s * 16 + t) * 64) + lane) * 8 + (k & 7)] = f2b(v);
}

// ---- fused cell: wave-independent, ZERO barriers ---------------------------
// Each wave owns 16 rows end-to-end: phase1 (stats via 4-lane shuffles,
// parked in wave-private LDS scalars) -> GEMM (A direct from global,
// wave-private rows, no duplication) -> epilogue (stats re-read from LDS).
// Intra-wave ds_write->ds_read ordering needs no barrier.  No lockstep:
// every wave always has issuable work -> smooth HBM demand.
// launch_bounds (256,2): round-0-verified config for acc[16] (VGPR ~120,
// no forced spill); LDS 34.5KB still admits 4 blocks/CU.
__global__ __launch_bounds__(256, 2)
void fused_cell(const float* __restrict__ inputs,
                const float* __restrict__ prev_h,
                const float* __restrict__ prev_G,
                const float* __restrict__ prev_phase,
                const ushort_t* __restrict__ Wp,
                const float* __restrict__ bias,
                float* __restrict__ out) {
    __shared__ __align__(16) short Gt[64 * GT_STRIDE];   // 33,792 B
    __shared__ float r_mean[64], r_rstd[64], r_comb[64]; // +768 B

    const int tid = threadIdx.x;
    const int w   = tid >> 6;
    const int l   = tid & 63;
    const int wr0 = blockIdx.x * 64 + w * 16;            // wave's first row

    float* outH = out;
    float* outG = out + (size_t)BATCH * UNITS;
    float* outP = out + (size_t)2 * BATCH * UNITS;

    short* GtW = Gt + (w * 16) * GT_STRIDE;              // wave-private slice

    // ---- phase 1: new_G = 0.9*prev_G + 0.1*roll(prev_h), stats, oscillator
    // 4 lanes per row (l>>2 = row, l&3 = 64B col slice), 16 iters, coalesced.
    const int prow = l >> 2;
    const int p    = l & 3;
    const int gr1  = wr0 + prow;

    float s1 = 0.f, s2 = 0.f, sh = 0.f;
    {
        const float* hpR = prev_h + (size_t)gr1 * UNITS;
        const float* gpR = prev_G + (size_t)gr1 * UNITS;
        float*       ogR = outG  + (size_t)gr1 * UNITS;
        #pragma unroll
        for (int i = 0; i < 16; ++i) {
            int c0 = i * 16 + p * 4;
            int pc = (c0 + 128) & 255;        // raw[:,c] = prev_h[:,(c+128)&255]
            float4 hp = *(const float4*)(hpR + pc);
            float4 gp = *(const float4*)(gpR + c0);
            float4 ng;
            ng.x = 0.9f * gp.x + 0.1f * hp.x;
            ng.y = 0.9f * gp.y + 0.1f * hp.y;
            ng.z = 0.9f * gp.z + 0.1f * hp.z;
            ng.w = 0.9f * gp.w + 0.1f * hp.w;
            s1 += ng.x + ng.y + ng.z + ng.w;
            s2 += ng.x*ng.x + ng.y*ng.y + ng.z*ng.z + ng.w*ng.w;
            sh += hp.x + hp.y + hp.z + hp.w;
            *(float4*)(ogR + c0) = ng;                            // output 1
            ushort4 gq; gq.x = f2b(ng.x); gq.y = f2b(ng.y);
            gq.z = f2b(ng.z); gq.w = f2b(ng.w);
            *(ushort4*)(GtW + prow * GT_STRIDE + c0) = gq;        // epilogue copy
        }
    }
    // 4-lane butterfly: all 4 lanes of the row group end with full sums
    s1 += __shfl_xor(s1, 1, 64); s1 += __shfl_xor(s1, 2, 64);
    s2 += __shfl_xor(s2, 1, 64); s2 += __shfl_xor(s2, 2, 64);
    sh += __shfl_xor(sh, 1, 64); sh += __shfl_xor(sh, 2, 64);
    if (p == 0) {
        float mean = s1 * (1.f / 256.f);
        float var  = s2 * (1.f / 256.f) - mean * mean;            // population
        float rstd = 1.f / (sqrtf(fmaxf(var, 0.f)) + 1e-6f);
        float np   = prev_phase[gr1] + 0.2513274122871834591f;    // 2*pi/25
        float comb = sinf(np) + 0.05f * (sh * (1.f / 256.f) - 0.1f);
        outP[gr1] = np;                                           // output 2
        int lrow = w * 16 + prow;
        r_mean[lrow] = mean; r_rstd[lrow] = rstd; r_comb[lrow] = comb;
    }

    // ---- GEMM: z = [inputs|prev_h] @ [w_in;w_rec]  (bf16 MFMA 16x16x32)
    // A[m=lane&15][k=q*8+j] direct from global (wave-private rows);
    // B streamed from packed Wp; C: col=lane&15, row=q*4+reg.
    const int n16 = l & 15;
    const int q   = l >> 4;
    const float* ainp = inputs + (size_t)(wr0 + n16) * UNITS + q * 8;
    const float* ahp  = prev_h + (size_t)(wr0 + n16) * UNITS + q * 8;
    const short* bw   = (const short*)Wp + l * 8;

    v4f acc[16];
    const v4f z4 = {0.f, 0.f, 0.f, 0.f};
    #pragma unroll
    for (int t = 0; t < 16; ++t) acc[t] = z4;

    #pragma unroll 2
    for (int s = 0; s < 8; ++s) {          // K-half 1: inputs
        float4 f0 = *(const float4*)(ainp + s * 32);
        float4 f1 = *(const float4*)(ainp + s * 32 + 4);
        v8s a;
        a[0] = (short)f2b(f0.x); a[1] = (short)f2b(f0.y);
        a[2] = (short)f2b(f0.z); a[3] = (short)f2b(f0.w);
        a[4] = (short)f2b(f1.x); a[5] = (short)f2b(f1.y);
        a[6] = (short)f2b(f1.z); a[7] = (short)f2b(f1.w);
        const short* bs = bw + s * 8192;
        #pragma unroll
        for (int t = 0; t < 16; ++t) {
            v8s b = *(const v8s*)(bs + t * 512);
            acc[t] = __builtin_amdgcn_mfma_f32_16x16x32_bf16(a, b, acc[t], 0, 0, 0);
        }
    }
    #pragma unroll 2
    for (int s = 8; s < 16; ++s) {         // K-half 2: prev_h (original order)
        float4 f0 = *(const float4*)(ahp + (s - 8) * 32);
        float4 f1 = *(const float4*)(ahp + (s - 8) * 32 + 4);
        v8s a;
        a[0] = (short)f2b(f0.x); a[1] = (short)f2b(f0.y);
        a[2] = (short)f2b(f0.z); a[3] = (short)f2b(f0.w);
        a[4] = (short)f2b(f1.x); a[5] = (short)f2b(f1.y);
        a[6] = (short)f2b(f1.z); a[7] = (short)f2b(f1.w);
        const short* bs = bw + s * 8192;
        #pragma unroll
        for (int t = 0; t < 16; ++t) {
            v8s b = *(const v8s*)(bs + t * 512);
            acc[t] = __builtin_amdgcn_mfma_f32_16x16x32_bf16(a, b, acc[t], 0, 0, 0);
        }
    }

    // stats for this lane's 4 output rows (q*4+r), from wave-private LDS
    float m_[4], rs_[4], cb_[4];
    #pragma unroll
    for (int r = 0; r < 4; ++r) {
        int lrr = w * 16 + q * 4 + r;
        m_[r]  = r_mean[lrr];
        rs_[r] = r_rstd[lrr];
        cb_[r] = r_comb[lrr];
    }

    // ---- epilogue: field_effect * (dot+bias) -> elu -> inertia -> clip
    #pragma unroll
    for (int t = 0; t < 16; ++t) {
        int c = t * 16 + n16;
        float bz = bias[c];
        #pragma unroll
        for (int r = 0; r < 4; ++r) {
            int lr = q * 4 + r;
            int gr = wr0 + lr;
            float gval = b2f((ushort_t)GtW[lr * GT_STRIDE + c]);
            float gn = (gval - m_[r]) * rs_[r];
            float e2 = __expf(2.f * gn);                   // tanh via exp
            float th = 1.f - 2.f / (e2 + 1.f);
            float field = 1.f + 0.5f * cb_[r] * th;
            float z = (acc[t][r] + bz) * field;
            float el = (z > 0.f) ? z : (__expf(z) - 1.f);
            float hprev = prev_h[(size_t)gr * UNITS + c];  // fp32, L1/L2-warm
            float h = 0.9f * hprev + 0.1f * el;
            h = fminf(fmaxf(h, -20.f), 20.f);
            outH[(size_t)gr * UNITS + c] = h;              // output 0
        }
    }
}

extern "C" void kernel_launch(void* const* d_in, const int* in_sizes, int n_in,
                              void* d_out, int out_size, void* d_ws, size_t ws_size,
                              hipStream_t stream) {
    const float* inputs     = (const float*)d_in[0];
    const float* prev_h     = (const float*)d_in[1];
    const float* prev_G     = (const float*)d_in[2];
    const float* prev_phase = (const float*)d_in[3];
    const float* w_in       = (const float*)d_in[4];
    const float* w_rec      = (const float*)d_in[5];
    const float* bias       = (const float*)d_in[6];
    float* out    = (float*)d_out;
    ushort_t* Wp  = (ushort_t*)d_ws;       // 262,144 B packed bf16 weights

    pack_w<<<512, 256, 0, stream>>>(w_in, w_rec, Wp);
    fused_cell<<<BATCH / 64, 256, 0, stream>>>(inputs, prev_h, prev_G,
                                               prev_phase, Wp, bias, out);
}